// Round 1
// baseline (8049.180 us; speedup 1.0000x reference)
//
#include <hip/hip_runtime.h>
#include <hip/hip_bf16.h>

#define SEQ_LEN 256
#define HIDDEN  2048
#define CLASSES 10
#define BATCH   128
#define NWG     256
#define WG_THREADS 512
#define STEPS   (SEQ_LEN - 1)
#define KTILES  64            // 2048 / 32

typedef __attribute__((ext_vector_type(8))) short  bf16x8;
typedef __attribute__((ext_vector_type(8))) unsigned short u16x8;
typedef __attribute__((ext_vector_type(4))) float  f32x4;
typedef __attribute__((ext_vector_type(4))) unsigned int u32x4;

// ---- workspace layout (bytes) ----
// [0, 33554432)                : WhPack  (bf16, MFMA B-fragment order, 256 WG x 128KB)
// [33554432, +524288)          : hA (bf16 [128][2048])
// [+524288,  +524288)          : hB
// [34603008, +1048576)         : h_final (fp32 [128][2048])
// [35651584, +512)             : barrier (cnt at [0], gen at [64])
#define WHP_OFF  0
#define HA_OFF   33554432UL
#define HB_OFF   (HA_OFF + 524288UL)
#define HF_OFF   (HB_OFF + 524288UL)
#define BAR_OFF  (HF_OFF + 1048576UL)

__device__ __forceinline__ unsigned short f2bf(float f) {
    unsigned int u = __float_as_uint(f);
    return (unsigned short)((u + 0x7FFFu + ((u >> 16) & 1u)) >> 16);
}
__device__ __forceinline__ float sigm(float z)  { return 1.0f / (1.0f + __expf(-z)); }
__device__ __forceinline__ float tanh_f(float z){ return 2.0f / (1.0f + __expf(-2.0f * z)) - 1.0f; }

// Pack Wh [2048][8192] fp32 -> bf16 in exact B-fragment order:
// chunk = ((W*64 + kt)*2 + nt)*64 + lane ; lane holds B[k=kt*32+(lane>>4)*8+j][n_local=nt*16+(lane&15)]
// n_local c32 = gate*8 + u  ->  n_global = gate*2048 + W*8 + u
__global__ void lstm_pack_kernel(const float* __restrict__ Wh,
                                 unsigned short* __restrict__ whp,
                                 unsigned short* __restrict__ hA,
                                 unsigned int* __restrict__ bar) {
    int chunk = blockIdx.x * 256 + threadIdx.x;     // 2,097,152 chunks total
    int lane = chunk & 63;
    int nt   = (chunk >> 6) & 1;
    int kt   = (chunk >> 7) & 63;
    int W    = chunk >> 13;
    int q = lane >> 4, l16 = lane & 15;
    int c32  = nt * 16 + l16;
    int gate = c32 >> 3, u = c32 & 7;
    int n    = gate * 2048 + W * 8 + u;
    int k0   = kt * 32 + q * 8;
    u16x8 frag;
    #pragma unroll
    for (int j = 0; j < 8; ++j)
        frag[j] = f2bf(Wh[(size_t)(k0 + j) * 8192 + n]);
    ((u16x8*)whp)[chunk] = frag;

    if (chunk < 32768) ((u32x4*)hA)[chunk] = (u32x4){0, 0, 0, 0};   // h0 = 0
    if (chunk == 0) { bar[0] = 0u; bar[64] = 0u; }
}

__device__ __forceinline__ void grid_barrier(unsigned int* cnt, unsigned int* gen) {
    __syncthreads();
    if (threadIdx.x == 0) {
        unsigned int g = __hip_atomic_load(gen, __ATOMIC_ACQUIRE, __HIP_MEMORY_SCOPE_AGENT);
        unsigned int t = __hip_atomic_fetch_add(cnt, 1u, __ATOMIC_ACQ_REL, __HIP_MEMORY_SCOPE_AGENT);
        if (t == NWG - 1u) {
            __hip_atomic_store(cnt, 0u, __ATOMIC_RELAXED, __HIP_MEMORY_SCOPE_AGENT);
            __hip_atomic_store(gen, g + 1u, __ATOMIC_RELEASE, __HIP_MEMORY_SCOPE_AGENT);
        } else {
            while (__hip_atomic_load(gen, __ATOMIC_ACQUIRE, __HIP_MEMORY_SCOPE_AGENT) == g)
                __builtin_amdgcn_s_sleep(1);
        }
    }
    __syncthreads();
}

__global__ __launch_bounds__(WG_THREADS, 2) void lstm_persist(
    const float* __restrict__ x,  const float* __restrict__ Wx,
    const float* __restrict__ b,  const float* __restrict__ Wph,
    const float* __restrict__ bp, const unsigned short* __restrict__ whp,
    unsigned short* hA, unsigned short* hB, float* hfin,
    unsigned int* bar, float* out)
{
    extern __shared__ char lds[];
    const int tid = threadIdx.x;
    const int W   = blockIdx.x;

    // stage this WG's Wh slice (128 KB) into LDS, layout identical to WhPack slice
    {
        const u32x4* src = (const u32x4*)whp + (size_t)W * 8192;
        u32x4* dst = (u32x4*)lds;
        for (int i = tid; i < 8192; i += WG_THREADS) dst[i] = src[i];
    }
    __syncthreads();

    const int lane = tid & 63;
    const int wv   = tid >> 6;          // wave 0..7 -> M-tile
    const int q    = lane >> 4;         // quad 0..3
    const int l16  = lane & 15;
    const int s    = (lane >> 3) & 1;   // 0: holds (g,f); 1: holds (i,o)
    const int u    = lane & 7;          // hidden unit within slice
    const int rowA = wv * 16 + l16;     // A row this lane loads
    const int row0 = wv * 16 + q * 4;   // C/D rows row0..row0+3
    const int colh = W * 8 + u;         // global hidden index this lane updates

    // per-lane Wx/b constants for its two z-columns (nt=0 -> c32=l16, nt=1 -> c32=16+l16)
    const int n0 = ((l16) >> 3) * 2048 + W * 8 + (l16 & 7);
    const int n1 = ((16 + l16) >> 3) * 2048 + W * 8 + ((16 + l16) & 7);
    const float wx0 = Wx[n0], bb0 = b[n0];
    const float wx1 = Wx[n1], bb1 = b[n1];

    float c_state[4] = {0.f, 0.f, 0.f, 0.f};
    unsigned short* hcur  = hA;
    unsigned short* hnext = hB;
    unsigned int* cnt = bar;
    unsigned int* gen = bar + 64;

    for (int t = 0; t < STEPS; ++t) {
        f32x4 acc0 = {0.f, 0.f, 0.f, 0.f};
        f32x4 acc1 = {0.f, 0.f, 0.f, 0.f};
        const bf16x8* ap = (const bf16x8*)hcur + rowA * 256 + q;   // 256 chunks/row
        const char* lp = lds + lane * 16;
        #pragma unroll 8
        for (int kt = 0; kt < KTILES; ++kt) {
            bf16x8 a  = ap[kt * 4];
            bf16x8 b0 = *(const bf16x8*)(lp + (kt * 2 + 0) * 1024);
            bf16x8 b1 = *(const bf16x8*)(lp + (kt * 2 + 1) * 1024);
            acc0 = __builtin_amdgcn_mfma_f32_16x16x32_bf16(a, b0, acc0, 0, 0, 0);
            acc1 = __builtin_amdgcn_mfma_f32_16x16x32_bf16(a, b1, acc1, 0, 0, 0);
        }

        const bool last = (t == STEPS - 1);
        #pragma unroll
        for (int r = 0; r < 4; ++r) {
            float xv = x[(row0 + r) * SEQ_LEN + t];
            float z0 = acc0[r] + xv * wx0 + bb0;
            float z1 = acc1[r] + xv * wx1 + bb1;
            float p0 = __shfl_xor(z0, 8, 64);
            float p1 = __shfl_xor(z1, 8, 64);
            float zg = s ? p0 : z0;
            float zi = s ? z0 : p0;
            float zf = s ? p1 : z1;
            float zo = s ? z1 : p1;
            float cn = tanh_f(zg) * sigm(zi) + c_state[r] * sigm(zf);
            c_state[r] = cn;
            float h = tanh_f(cn) * sigm(zo);
            if (s == 0) {
                int row = row0 + r;
                hnext[row * HIDDEN + colh] = f2bf(h);
                if (last) hfin[row * HIDDEN + colh] = h;
            }
        }
        grid_barrier(cnt, gen);
        unsigned short* tmp = hcur; hcur = hnext; hnext = tmp;
    }

    // ---- classifier + softmax epilogue: WG b handles batch row b ----
    if (W < BATCH) {
        float part[CLASSES];
        #pragma unroll
        for (int c = 0; c < CLASSES; ++c) part[c] = 0.f;
        for (int k = tid; k < HIDDEN; k += WG_THREADS) {
            float hv = hfin[W * HIDDEN + k];
            #pragma unroll
            for (int c = 0; c < CLASSES; ++c) part[c] += hv * Wph[k * CLASSES + c];
        }
        #pragma unroll
        for (int c = 0; c < CLASSES; ++c)
            for (int off = 32; off > 0; off >>= 1)
                part[c] += __shfl_xor(part[c], off, 64);
        float* red = (float*)lds;
        __syncthreads();
        if (lane == 0)
            for (int c = 0; c < CLASSES; ++c) red[wv * CLASSES + c] = part[c];
        __syncthreads();
        if (tid == 0) {
            float lg[CLASSES];
            for (int c = 0; c < CLASSES; ++c) {
                float sm = bp[c];
                for (int w8 = 0; w8 < 8; ++w8) sm += red[w8 * CLASSES + c];
                lg[c] = sm;
            }
            float mx = lg[0];
            for (int c = 1; c < CLASSES; ++c) mx = fmaxf(mx, lg[c]);
            float se = 0.f;
            for (int c = 0; c < CLASSES; ++c) { lg[c] = __expf(lg[c] - mx); se += lg[c]; }
            float inv = 1.0f / se;
            for (int c = 0; c < CLASSES; ++c) out[W * CLASSES + c] = lg[c] * inv;
        }
    }
}

extern "C" void kernel_launch(void* const* d_in, const int* in_sizes, int n_in,
                              void* d_out, int out_size, void* d_ws, size_t ws_size,
                              hipStream_t stream) {
    const float* x   = (const float*)d_in[0];
    const float* Wx  = (const float*)d_in[1];
    const float* Wh  = (const float*)d_in[2];
    const float* b   = (const float*)d_in[3];
    const float* Wph = (const float*)d_in[4];
    const float* bp  = (const float*)d_in[5];
    float* out = (float*)d_out;

    char* ws = (char*)d_ws;
    unsigned short* whp = (unsigned short*)(ws + WHP_OFF);
    unsigned short* hA  = (unsigned short*)(ws + HA_OFF);
    unsigned short* hB  = (unsigned short*)(ws + HB_OFF);
    float*          hfin= (float*)(ws + HF_OFF);
    unsigned int*   bar = (unsigned int*)(ws + BAR_OFF);

    hipFuncSetAttribute((const void*)lstm_persist,
                        hipFuncAttributeMaxDynamicSharedMemorySize, 131072);

    lstm_pack_kernel<<<8192, 256, 0, stream>>>(Wh, whp, hA, bar);
    lstm_persist<<<NWG, WG_THREADS, 131072, stream>>>(x, Wx, b, Wph, bp,
                                                      whp, hA, hB, hfin, bar, out);
}

// Round 2
// 6387.187 us; speedup vs baseline: 1.2602x; 1.2602x over previous
//
#include <hip/hip_runtime.h>
#include <hip/hip_bf16.h>

#define SEQ_LEN 256
#define HIDDEN  2048
#define CLASSES 10
#define BATCH   128
#define NWG     256
#define WG_THREADS 512
#define STEPS   (SEQ_LEN - 1)
#define KTILES  64            // 2048 / 32

typedef __attribute__((ext_vector_type(8))) short  bf16x8;
typedef __attribute__((ext_vector_type(8))) unsigned short u16x8;
typedef __attribute__((ext_vector_type(4))) float  f32x4;
typedef __attribute__((ext_vector_type(4))) unsigned int u32x4;

// ---- workspace layout (bytes) ----
#define WHP_OFF  0
#define HA_OFF   33554432UL
#define HB_OFF   (HA_OFF + 524288UL)
#define HF_OFF   (HB_OFF + 524288UL)
#define BAR_OFF  (HF_OFF + 1048576UL)
// bar layout (uints): [0] root ; [32 + 32*j] leaf j (j=0..7), 128B apart

__device__ __forceinline__ unsigned short f2bf(float f) {
    unsigned int u = __float_as_uint(f);
    return (unsigned short)((u + 0x7FFFu + ((u >> 16) & 1u)) >> 16);
}
__device__ __forceinline__ float sigm(float z)  { return 1.0f / (1.0f + __expf(-z)); }
__device__ __forceinline__ float tanh_f(float z){ return 2.0f / (1.0f + __expf(-2.0f * z)) - 1.0f; }

// Pack Wh [2048][8192] fp32 -> bf16 in exact MFMA B-fragment order (see R1 notes).
__global__ void lstm_pack_kernel(const float* __restrict__ Wh,
                                 unsigned short* __restrict__ whp,
                                 unsigned short* __restrict__ hA,
                                 unsigned int* __restrict__ bar) {
    int chunk = blockIdx.x * 256 + threadIdx.x;     // 2,097,152 chunks total
    int lane = chunk & 63;
    int nt   = (chunk >> 6) & 1;
    int kt   = (chunk >> 7) & 63;
    int W    = chunk >> 13;
    int q = lane >> 4, l16 = lane & 15;
    int c32  = nt * 16 + l16;
    int gate = c32 >> 3, u = c32 & 7;
    int n    = gate * 2048 + W * 8 + u;
    int k0   = kt * 32 + q * 8;
    u16x8 frag;
    #pragma unroll
    for (int j = 0; j < 8; ++j)
        frag[j] = f2bf(Wh[(size_t)(k0 + j) * 8192 + n]);
    ((u16x8*)whp)[chunk] = frag;

    if (chunk < 32768) ((u32x4*)hA)[chunk] = (u32x4){0, 0, 0, 0};   // h0 = 0
    if (chunk < 512) bar[chunk] = 0u;                               // all barrier counters
}

// Monotonic hierarchical barrier: 8 leaf counters (128B apart) -> 1 root.
// RELAXED atomics only; exactly one release fence (wbl2) before arrival and
// one acquire fence (inv) after the flip — per WG per step.
__device__ __forceinline__ void grid_barrier(unsigned int* bar, unsigned int phase1) {
    __syncthreads();
    if (threadIdx.x == 0) {
        __builtin_amdgcn_fence(__ATOMIC_RELEASE, "agent");   // one wbl2: push h to L3
        unsigned int* leaf = bar + 32 + 32 * (blockIdx.x & 7);
        unsigned int old = __hip_atomic_fetch_add(leaf, 1u, __ATOMIC_RELAXED,
                                                  __HIP_MEMORY_SCOPE_AGENT);
        if (old == phase1 * 32u - 1u)                        // 32nd arrival on this leaf
            __hip_atomic_fetch_add(bar, 1u, __ATOMIC_RELAXED, __HIP_MEMORY_SCOPE_AGENT);
        while (__hip_atomic_load(bar, __ATOMIC_RELAXED, __HIP_MEMORY_SCOPE_AGENT)
               < phase1 * 8u)
            __builtin_amdgcn_s_sleep(1);
        __builtin_amdgcn_fence(__ATOMIC_ACQUIRE, "agent");   // one inv: next h reads refill from L3
    }
    __syncthreads();
}

__global__ __launch_bounds__(WG_THREADS, 2) void lstm_persist(
    const float* __restrict__ x,  const float* __restrict__ Wx,
    const float* __restrict__ b,  const float* __restrict__ Wph,
    const float* __restrict__ bp, const unsigned short* __restrict__ whp,
    unsigned short* hA, unsigned short* hB, float* hfin,
    unsigned int* bar, float* out)
{
    extern __shared__ char lds[];
    const int tid = threadIdx.x;
    const int W   = blockIdx.x;

    // stage this WG's Wh slice (128 KB) into LDS
    {
        const u32x4* src = (const u32x4*)whp + (size_t)W * 8192;
        u32x4* dst = (u32x4*)lds;
        for (int i = tid; i < 8192; i += WG_THREADS) dst[i] = src[i];
    }
    __syncthreads();

    const int lane = tid & 63;
    const int wv   = tid >> 6;          // wave 0..7 -> M-tile
    const int q    = lane >> 4;         // quad 0..3
    const int l16  = lane & 15;
    const int s    = (lane >> 3) & 1;   // 0: holds (g,f); 1: holds (i,o)
    const int u    = lane & 7;          // hidden unit within slice
    const int rowA = wv * 16 + l16;     // A row this lane loads
    const int row0 = wv * 16 + q * 4;   // C/D rows row0..row0+3
    const int colh = W * 8 + u;         // global hidden index this lane updates

    const int n0 = ((l16) >> 3) * 2048 + W * 8 + (l16 & 7);
    const int n1 = ((16 + l16) >> 3) * 2048 + W * 8 + ((16 + l16) & 7);
    const float wx0 = Wx[n0], bb0 = b[n0];
    const float wx1 = Wx[n1], bb1 = b[n1];

    float c_state[4] = {0.f, 0.f, 0.f, 0.f};
    unsigned short* hcur  = hA;
    unsigned short* hnext = hB;

    for (int t = 0; t < STEPS; ++t) {
        f32x4 acc0 = {0.f, 0.f, 0.f, 0.f};
        f32x4 acc1 = {0.f, 0.f, 0.f, 0.f};
        const bf16x8* ap = (const bf16x8*)hcur + rowA * 256 + q;   // 256 chunks/row
        const char* lp = lds + lane * 16;
        #pragma unroll 8
        for (int kt = 0; kt < KTILES; ++kt) {
            bf16x8 a  = ap[kt * 4];
            bf16x8 b0 = *(const bf16x8*)(lp + (kt * 2 + 0) * 1024);
            bf16x8 b1 = *(const bf16x8*)(lp + (kt * 2 + 1) * 1024);
            acc0 = __builtin_amdgcn_mfma_f32_16x16x32_bf16(a, b0, acc0, 0, 0, 0);
            acc1 = __builtin_amdgcn_mfma_f32_16x16x32_bf16(a, b1, acc1, 0, 0, 0);
        }

        const bool last = (t == STEPS - 1);
        #pragma unroll
        for (int r = 0; r < 4; ++r) {
            float xv = x[(row0 + r) * SEQ_LEN + t];
            float z0 = acc0[r] + xv * wx0 + bb0;
            float z1 = acc1[r] + xv * wx1 + bb1;
            float p0 = __shfl_xor(z0, 8, 64);
            float p1 = __shfl_xor(z1, 8, 64);
            float zg = s ? p0 : z0;
            float zi = s ? z0 : p0;
            float zf = s ? p1 : z1;
            float zo = s ? z1 : p1;
            float cn = tanh_f(zg) * sigm(zi) + c_state[r] * sigm(zf);
            c_state[r] = cn;
            float h = tanh_f(cn) * sigm(zo);
            if (s == 0) {
                int row = row0 + r;
                hnext[row * HIDDEN + colh] = f2bf(h);
                if (last) hfin[row * HIDDEN + colh] = h;
            }
        }
        grid_barrier(bar, (unsigned int)(t + 1));
        unsigned short* tmp = hcur; hcur = hnext; hnext = tmp;
    }

    // ---- classifier + softmax epilogue: WG b handles batch row b ----
    if (W < BATCH) {
        float part[CLASSES];
        #pragma unroll
        for (int c = 0; c < CLASSES; ++c) part[c] = 0.f;
        for (int k = tid; k < HIDDEN; k += WG_THREADS) {
            float hv = hfin[W * HIDDEN + k];
            #pragma unroll
            for (int c = 0; c < CLASSES; ++c) part[c] += hv * Wph[k * CLASSES + c];
        }
        #pragma unroll
        for (int c = 0; c < CLASSES; ++c)
            for (int off = 32; off > 0; off >>= 1)
                part[c] += __shfl_xor(part[c], off, 64);
        float* red = (float*)lds;
        __syncthreads();
        if (lane == 0)
            for (int c = 0; c < CLASSES; ++c) red[wv * CLASSES + c] = part[c];
        __syncthreads();
        if (tid == 0) {
            float lg[CLASSES];
            for (int c = 0; c < CLASSES; ++c) {
                float sm = bp[c];
                for (int w8 = 0; w8 < 8; ++w8) sm += red[w8 * CLASSES + c];
                lg[c] = sm;
            }
            float mx = lg[0];
            for (int c = 1; c < CLASSES; ++c) mx = fmaxf(mx, lg[c]);
            float se = 0.f;
            for (int c = 0; c < CLASSES; ++c) { lg[c] = __expf(lg[c] - mx); se += lg[c]; }
            float inv = 1.0f / se;
            for (int c = 0; c < CLASSES; ++c) out[W * CLASSES + c] = lg[c] * inv;
        }
    }
}

extern "C" void kernel_launch(void* const* d_in, const int* in_sizes, int n_in,
                              void* d_out, int out_size, void* d_ws, size_t ws_size,
                              hipStream_t stream) {
    const float* x   = (const float*)d_in[0];
    const float* Wx  = (const float*)d_in[1];
    const float* Wh  = (const float*)d_in[2];
    const float* b   = (const float*)d_in[3];
    const float* Wph = (const float*)d_in[4];
    const float* bp  = (const float*)d_in[5];
    float* out = (float*)d_out;

    char* ws = (char*)d_ws;
    unsigned short* whp = (unsigned short*)(ws + WHP_OFF);
    unsigned short* hA  = (unsigned short*)(ws + HA_OFF);
    unsigned short* hB  = (unsigned short*)(ws + HB_OFF);
    float*          hfin= (float*)(ws + HF_OFF);
    unsigned int*   bar = (unsigned int*)(ws + BAR_OFF);

    hipFuncSetAttribute((const void*)lstm_persist,
                        hipFuncAttributeMaxDynamicSharedMemorySize, 131072);

    lstm_pack_kernel<<<8192, 256, 0, stream>>>(Wh, whp, hA, bar);
    lstm_persist<<<NWG, WG_THREADS, 131072, stream>>>(x, Wx, b, Wph, bp,
                                                      whp, hA, hB, hfin, bar, out);
}

// Round 3
// 5105.246 us; speedup vs baseline: 1.5766x; 1.2511x over previous
//
#include <hip/hip_runtime.h>
#include <hip/hip_bf16.h>

#define SEQ_LEN 256
#define HIDDEN  2048
#define CLASSES 10
#define BATCH   128
#define NWG     256
#define WG_THREADS 512
#define STEPS   (SEQ_LEN - 1)
#define KTILES  64            // 2048 / 32

typedef __attribute__((ext_vector_type(8))) short  bf16x8;
typedef __attribute__((ext_vector_type(8))) unsigned short u16x8;
typedef __attribute__((ext_vector_type(4))) float  f32x4;
typedef __attribute__((ext_vector_type(4))) unsigned int u32x4;

// ---- workspace layout (bytes) ----
#define WHP_OFF  0
#define HA_OFF   33554432UL
#define HB_OFF   (HA_OFF + 524288UL)
#define HF_OFF   (HB_OFF + 524288UL)
#define BAR_OFF  (HF_OFF + 1048576UL)
// bar layout (uints): [0] root ; [32 + 32*j] leaf j (j=0..7), 128B apart

__device__ __forceinline__ unsigned short f2bf(float f) {
    unsigned int u = __float_as_uint(f);
    return (unsigned short)((u + 0x7FFFu + ((u >> 16) & 1u)) >> 16);
}
__device__ __forceinline__ float sigm(float z)  { return 1.0f / (1.0f + __expf(-z)); }
__device__ __forceinline__ float tanh_f(float z){ return 2.0f / (1.0f + __expf(-2.0f * z)) - 1.0f; }

// Pack Wh [2048][8192] fp32 -> bf16 in exact MFMA B-fragment order (see R1 notes).
__global__ void lstm_pack_kernel(const float* __restrict__ Wh,
                                 unsigned short* __restrict__ whp,
                                 unsigned short* __restrict__ hA,
                                 unsigned int* __restrict__ bar) {
    int chunk = blockIdx.x * 256 + threadIdx.x;     // 2,097,152 chunks total
    int lane = chunk & 63;
    int nt   = (chunk >> 6) & 1;
    int kt   = (chunk >> 7) & 63;
    int W    = chunk >> 13;
    int q = lane >> 4, l16 = lane & 15;
    int c32  = nt * 16 + l16;
    int gate = c32 >> 3, u = c32 & 7;
    int n    = gate * 2048 + W * 8 + u;
    int k0   = kt * 32 + q * 8;
    u16x8 frag;
    #pragma unroll
    for (int j = 0; j < 8; ++j)
        frag[j] = f2bf(Wh[(size_t)(k0 + j) * 8192 + n]);
    ((u16x8*)whp)[chunk] = frag;

    if (chunk < 32768) ((u32x4*)hA)[chunk] = (u32x4){0, 0, 0, 0};   // h0 = 0
    if (chunk < 512) bar[chunk] = 0u;                               // all barrier counters
}

// Monotonic hierarchical barrier. All cross-WG data is stored write-through
// (agent-scope relaxed atomic stores -> sc1), so NO release fence (wbl2) is
// needed: __syncthreads' vmcnt(0) drain pushes the stores to the coherence
// point before arrival. One cheap acquire fence (inv) after the flip so the
// cached (normal, L2-dedup'd) h reads refill from L3.
__device__ __forceinline__ void grid_barrier(unsigned int* bar, unsigned int phase1) {
    __syncthreads();   // implies s_waitcnt vmcnt(0): write-through h stores are at L3
    if (threadIdx.x == 0) {
        unsigned int* leaf = bar + 32 + 32 * (blockIdx.x & 7);
        unsigned int old = __hip_atomic_fetch_add(leaf, 1u, __ATOMIC_RELAXED,
                                                  __HIP_MEMORY_SCOPE_AGENT);
        if (old == phase1 * 32u - 1u)                        // 32nd arrival on this leaf
            __hip_atomic_fetch_add(bar, 1u, __ATOMIC_RELAXED, __HIP_MEMORY_SCOPE_AGENT);
        while (__hip_atomic_load(bar, __ATOMIC_RELAXED, __HIP_MEMORY_SCOPE_AGENT)
               < phase1 * 8u)
            __builtin_amdgcn_s_sleep(1);
        __builtin_amdgcn_fence(__ATOMIC_ACQUIRE, "agent");   // inv L1+L2 (cheap, per R1/R2 A/B)
    }
    __syncthreads();
}

__global__ __launch_bounds__(WG_THREADS, 2) void lstm_persist(
    const float* __restrict__ x,  const float* __restrict__ Wx,
    const float* __restrict__ b,  const float* __restrict__ Wph,
    const float* __restrict__ bp, const unsigned short* __restrict__ whp,
    unsigned short* hA, unsigned short* hB, float* hfin,
    unsigned int* bar, float* out)
{
    extern __shared__ char lds[];
    const int tid = threadIdx.x;
    const int W   = blockIdx.x;

    // stage this WG's Wh slice (128 KB) into LDS
    {
        const u32x4* src = (const u32x4*)whp + (size_t)W * 8192;
        u32x4* dst = (u32x4*)lds;
        for (int i = tid; i < 8192; i += WG_THREADS) dst[i] = src[i];
    }
    __syncthreads();

    const int lane = tid & 63;
    const int wv   = tid >> 6;          // wave 0..7 -> M-tile
    const int q    = lane >> 4;         // quad 0..3
    const int l16  = lane & 15;
    const int s    = (lane >> 3) & 1;   // 0: holds (g,f); 1: holds (i,o)
    const int u    = lane & 7;          // hidden unit within slice
    const int rowA = wv * 16 + l16;     // A row this lane loads
    const int row0 = wv * 16 + q * 4;   // C/D rows row0..row0+3
    const int colh = W * 8 + u;         // global hidden index this lane updates

    const int n0 = ((l16) >> 3) * 2048 + W * 8 + (l16 & 7);
    const int n1 = ((16 + l16) >> 3) * 2048 + W * 8 + ((16 + l16) & 7);
    const float wx0 = Wx[n0], bb0 = b[n0];
    const float wx1 = Wx[n1], bb1 = b[n1];

    float c_state[4] = {0.f, 0.f, 0.f, 0.f};
    unsigned short* hcur  = hA;
    unsigned short* hnext = hB;

    for (int t = 0; t < STEPS; ++t) {
        // hoist x loads above the MFMA loop (they miss L2 after the inv)
        float xv[4];
        #pragma unroll
        for (int r = 0; r < 4; ++r) xv[r] = x[(row0 + r) * SEQ_LEN + t];

        f32x4 acc0 = {0.f, 0.f, 0.f, 0.f};
        f32x4 acc1 = {0.f, 0.f, 0.f, 0.f};
        const bf16x8* ap = (const bf16x8*)hcur + rowA * 256 + q;   // 256 chunks/row
        const char* lp = lds + lane * 16;
        #pragma unroll 8
        for (int kt = 0; kt < KTILES; ++kt) {
            bf16x8 a  = ap[kt * 4];
            bf16x8 b0 = *(const bf16x8*)(lp + (kt * 2 + 0) * 1024);
            bf16x8 b1 = *(const bf16x8*)(lp + (kt * 2 + 1) * 1024);
            acc0 = __builtin_amdgcn_mfma_f32_16x16x32_bf16(a, b0, acc0, 0, 0, 0);
            acc1 = __builtin_amdgcn_mfma_f32_16x16x32_bf16(a, b1, acc1, 0, 0, 0);
        }

        const bool last = (t == STEPS - 1);
        #pragma unroll
        for (int r = 0; r < 4; ++r) {
            float z0 = acc0[r] + xv[r] * wx0 + bb0;
            float z1 = acc1[r] + xv[r] * wx1 + bb1;
            float p0 = __shfl_xor(z0, 8, 64);
            float p1 = __shfl_xor(z1, 8, 64);
            float zg = s ? p0 : z0;
            float zi = s ? z0 : p0;
            float zf = s ? p1 : z1;
            float zo = s ? z1 : p1;
            float cn = tanh_f(zg) * sigm(zi) + c_state[r] * sigm(zf);
            c_state[r] = cn;
            float h = tanh_f(cn) * sigm(zo);
            // lanes u and u^1 hold adjacent columns (same rows); pack 2 bf16 -> 4B
            float hn = __shfl_xor(h, 1, 64);
            int row = row0 + r;
            if ((lane & 9) == 0) {   // s==0 && u even
                unsigned int packed = (unsigned int)f2bf(h)
                                    | ((unsigned int)f2bf(hn) << 16);
                __hip_atomic_store((unsigned int*)&hnext[row * HIDDEN + colh], packed,
                                   __ATOMIC_RELAXED, __HIP_MEMORY_SCOPE_AGENT);
            }
            if (last && s == 0) {
                __hip_atomic_store(&hfin[row * HIDDEN + colh], h,
                                   __ATOMIC_RELAXED, __HIP_MEMORY_SCOPE_AGENT);
            }
        }
        grid_barrier(bar, (unsigned int)(t + 1));
        unsigned short* tmp = hcur; hcur = hnext; hnext = tmp;
    }

    // ---- classifier + softmax epilogue: WG b handles batch row b ----
    if (W < BATCH) {
        float part[CLASSES];
        #pragma unroll
        for (int c = 0; c < CLASSES; ++c) part[c] = 0.f;
        for (int k = tid; k < HIDDEN; k += WG_THREADS) {
            float hv = hfin[W * HIDDEN + k];
            #pragma unroll
            for (int c = 0; c < CLASSES; ++c) part[c] += hv * Wph[k * CLASSES + c];
        }
        #pragma unroll
        for (int c = 0; c < CLASSES; ++c)
            for (int off = 32; off > 0; off >>= 1)
                part[c] += __shfl_xor(part[c], off, 64);
        float* red = (float*)lds;
        __syncthreads();
        if (lane == 0)
            for (int c = 0; c < CLASSES; ++c) red[wv * CLASSES + c] = part[c];
        __syncthreads();
        if (tid == 0) {
            float lg[CLASSES];
            for (int c = 0; c < CLASSES; ++c) {
                float sm = bp[c];
                for (int w8 = 0; w8 < 8; ++w8) sm += red[w8 * CLASSES + c];
                lg[c] = sm;
            }
            float mx = lg[0];
            for (int c = 1; c < CLASSES; ++c) mx = fmaxf(mx, lg[c]);
            float se = 0.f;
            for (int c = 0; c < CLASSES; ++c) { lg[c] = __expf(lg[c] - mx); se += lg[c]; }
            float inv = 1.0f / se;
            for (int c = 0; c < CLASSES; ++c) out[W * CLASSES + c] = lg[c] * inv;
        }
    }
}

extern "C" void kernel_launch(void* const* d_in, const int* in_sizes, int n_in,
                              void* d_out, int out_size, void* d_ws, size_t ws_size,
                              hipStream_t stream) {
    const float* x   = (const float*)d_in[0];
    const float* Wx  = (const float*)d_in[1];
    const float* Wh  = (const float*)d_in[2];
    const float* b   = (const float*)d_in[3];
    const float* Wph = (const float*)d_in[4];
    const float* bp  = (const float*)d_in[5];
    float* out = (float*)d_out;

    char* ws = (char*)d_ws;
    unsigned short* whp = (unsigned short*)(ws + WHP_OFF);
    unsigned short* hA  = (unsigned short*)(ws + HA_OFF);
    unsigned short* hB  = (unsigned short*)(ws + HB_OFF);
    float*          hfin= (float*)(ws + HF_OFF);
    unsigned int*   bar = (unsigned int*)(ws + BAR_OFF);

    hipFuncSetAttribute((const void*)lstm_persist,
                        hipFuncAttributeMaxDynamicSharedMemorySize, 131072);

    lstm_pack_kernel<<<8192, 256, 0, stream>>>(Wh, whp, hA, bar);
    lstm_persist<<<NWG, WG_THREADS, 131072, stream>>>(x, Wx, b, Wph, bp,
                                                      whp, hA, hB, hfin, bar, out);
}

// Round 4
// 4821.924 us; speedup vs baseline: 1.6693x; 1.0588x over previous
//
#include <hip/hip_runtime.h>
#include <hip/hip_bf16.h>

#define SEQ_LEN 256
#define HIDDEN  2048
#define CLASSES 10
#define BATCH   128
#define NWG     256
#define WG_THREADS 512
#define STEPS   (SEQ_LEN - 1)
#define KTILES  64            // 2048 / 32
#define NBUF    4             // rotating h buffers; inv every NBUF steps

typedef __attribute__((ext_vector_type(8))) short  bf16x8;
typedef __attribute__((ext_vector_type(8))) unsigned short u16x8;
typedef __attribute__((ext_vector_type(4))) float  f32x4;
typedef __attribute__((ext_vector_type(4))) unsigned int u32x4;

// ---- workspace layout (bytes) ----
#define WHP_OFF  0
#define HB_OFF   33554432UL                    // 4 x 512 KB rotating h buffers
#define HF_OFF   (HB_OFF + 4UL * 524288UL)     // fp32 h_final [128][2048]
#define BAR_OFF  (HF_OFF + 1048576UL)
// bar layout (uints): [0] root ; [32 + 32*j] leaf j (j=0..7), 128B apart

__device__ __forceinline__ unsigned short f2bf(float f) {
    unsigned int u = __float_as_uint(f);
    return (unsigned short)((u + 0x7FFFu + ((u >> 16) & 1u)) >> 16);
}
__device__ __forceinline__ float sigm(float z)  { return 1.0f / (1.0f + __expf(-z)); }
__device__ __forceinline__ float tanh_f(float z){ return 2.0f / (1.0f + __expf(-2.0f * z)) - 1.0f; }

// Pack Wh [2048][8192] fp32 -> bf16 in exact MFMA B-fragment order (see R1 notes).
__global__ void lstm_pack_kernel(const float* __restrict__ Wh,
                                 unsigned short* __restrict__ whp,
                                 unsigned short* __restrict__ hbufs,
                                 unsigned int* __restrict__ bar) {
    int chunk = blockIdx.x * 256 + threadIdx.x;     // 2,097,152 chunks total
    int lane = chunk & 63;
    int nt   = (chunk >> 6) & 1;
    int kt   = (chunk >> 7) & 63;
    int W    = chunk >> 13;
    int q = lane >> 4, l16 = lane & 15;
    int c32  = nt * 16 + l16;
    int gate = c32 >> 3, u = c32 & 7;
    int n    = gate * 2048 + W * 8 + u;
    int k0   = kt * 32 + q * 8;
    u16x8 frag;
    #pragma unroll
    for (int j = 0; j < 8; ++j)
        frag[j] = f2bf(Wh[(size_t)(k0 + j) * 8192 + n]);
    ((u16x8*)whp)[chunk] = frag;

    if (chunk < 32768) ((u32x4*)hbufs)[chunk] = (u32x4){0, 0, 0, 0};   // buf0: h(0)=0
    if (chunk < 512) bar[chunk] = 0u;                                  // barrier counters
}

// Monotonic hierarchical barrier (8 leaves -> 1 root), RELAXED atomics only.
// Stores are write-through sc1 (drained by __syncthreads' vmcnt(0)) -> no
// release fence ever. Acquire fence (buffer_inv) only when do_inv: with NBUF
// rotating h buffers, a stale L2 copy can only be NBUF steps old, so one inv
// per NBUF barriers suffices.
__device__ __forceinline__ void grid_barrier(unsigned int* bar, unsigned int phase1,
                                             bool do_inv) {
    __syncthreads();   // implies s_waitcnt vmcnt(0): sc1 h stores are at L3
    if (threadIdx.x == 0) {
        unsigned int* leaf = bar + 32 + 32 * (blockIdx.x & 7);
        unsigned int old = __hip_atomic_fetch_add(leaf, 1u, __ATOMIC_RELAXED,
                                                  __HIP_MEMORY_SCOPE_AGENT);
        if (old == phase1 * 32u - 1u)                        // 32nd arrival on this leaf
            __hip_atomic_fetch_add(bar, 1u, __ATOMIC_RELAXED, __HIP_MEMORY_SCOPE_AGENT);
        while (__hip_atomic_load(bar, __ATOMIC_RELAXED, __HIP_MEMORY_SCOPE_AGENT)
               < phase1 * 8u)
            __builtin_amdgcn_s_sleep(1);
        if (do_inv)
            __builtin_amdgcn_fence(__ATOMIC_ACQUIRE, "agent");   // buffer_inv
    }
    __syncthreads();
}

__global__ __launch_bounds__(WG_THREADS, 2) void lstm_persist(
    const float* __restrict__ x,  const float* __restrict__ Wx,
    const float* __restrict__ b,  const float* __restrict__ Wph,
    const float* __restrict__ bp, const unsigned short* __restrict__ whp,
    unsigned short* hbufs, float* hfin,
    unsigned int* bar, float* out)
{
    extern __shared__ char lds[];
    const int tid = threadIdx.x;
    const int W   = blockIdx.x;

    // stage this WG's Wh slice (128 KB) into LDS
    {
        const u32x4* src = (const u32x4*)whp + (size_t)W * 8192;
        u32x4* dst = (u32x4*)lds;
        for (int i = tid; i < 8192; i += WG_THREADS) dst[i] = src[i];
    }
    __syncthreads();

    const int lane = tid & 63;
    const int wv   = tid >> 6;          // wave 0..7 -> M-tile
    const int q    = lane >> 4;         // quad 0..3
    const int l16  = lane & 15;
    const int s    = (lane >> 3) & 1;   // 0: holds (g,f); 1: holds (i,o)
    const int u    = lane & 7;          // hidden unit within slice
    const int rowA = wv * 16 + l16;     // A row this lane loads
    const int row0 = wv * 16 + q * 4;   // C/D rows row0..row0+3
    const int colh = W * 8 + u;         // global hidden index this lane updates

    const int n0 = ((l16) >> 3) * 2048 + W * 8 + (l16 & 7);
    const int n1 = ((16 + l16) >> 3) * 2048 + W * 8 + ((16 + l16) & 7);
    const float wx0 = Wx[n0], bb0 = b[n0];
    const float wx1 = Wx[n1], bb1 = b[n1];

    float c_state[4] = {0.f, 0.f, 0.f, 0.f};

    for (int t = 0; t < STEPS; ++t) {
        unsigned short* hcur  = hbufs + (size_t)(t & 3) * 262144;        // elements
        unsigned short* hnext = hbufs + (size_t)((t + 1) & 3) * 262144;

        float xv[4];
        #pragma unroll
        for (int r = 0; r < 4; ++r) xv[r] = x[(row0 + r) * SEQ_LEN + t];

        f32x4 acc0 = {0.f, 0.f, 0.f, 0.f};
        f32x4 acc1 = {0.f, 0.f, 0.f, 0.f};
        const bf16x8* ap = (const bf16x8*)hcur + rowA * 256 + q;   // 256 chunks/row
        const char* lp = lds + lane * 16;
        bf16x8 a_cur = ap[0];
        #pragma unroll 8
        for (int kt = 0; kt < KTILES - 1; ++kt) {
            bf16x8 a_nxt = ap[(kt + 1) * 4];                 // depth-1 prefetch
            bf16x8 b0 = *(const bf16x8*)(lp + (kt * 2 + 0) * 1024);
            bf16x8 b1 = *(const bf16x8*)(lp + (kt * 2 + 1) * 1024);
            acc0 = __builtin_amdgcn_mfma_f32_16x16x32_bf16(a_cur, b0, acc0, 0, 0, 0);
            acc1 = __builtin_amdgcn_mfma_f32_16x16x32_bf16(a_cur, b1, acc1, 0, 0, 0);
            a_cur = a_nxt;
        }
        {
            const int kt = KTILES - 1;
            bf16x8 b0 = *(const bf16x8*)(lp + (kt * 2 + 0) * 1024);
            bf16x8 b1 = *(const bf16x8*)(lp + (kt * 2 + 1) * 1024);
            acc0 = __builtin_amdgcn_mfma_f32_16x16x32_bf16(a_cur, b0, acc0, 0, 0, 0);
            acc1 = __builtin_amdgcn_mfma_f32_16x16x32_bf16(a_cur, b1, acc1, 0, 0, 0);
        }

        const bool last = (t == STEPS - 1);
        #pragma unroll
        for (int r = 0; r < 4; ++r) {
            float z0 = acc0[r] + xv[r] * wx0 + bb0;
            float z1 = acc1[r] + xv[r] * wx1 + bb1;
            float p0 = __shfl_xor(z0, 8, 64);
            float p1 = __shfl_xor(z1, 8, 64);
            float zg = s ? p0 : z0;
            float zi = s ? z0 : p0;
            float zf = s ? p1 : z1;
            float zo = s ? z1 : p1;
            float cn = tanh_f(zg) * sigm(zi) + c_state[r] * sigm(zf);
            c_state[r] = cn;
            float h = tanh_f(cn) * sigm(zo);
            // lanes u and u^1 hold adjacent columns (same rows); pack 2 bf16 -> 4B
            float hn = __shfl_xor(h, 1, 64);
            int row = row0 + r;
            if ((lane & 9) == 0) {   // s==0 && u even
                unsigned int packed = (unsigned int)f2bf(h)
                                    | ((unsigned int)f2bf(hn) << 16);
                __hip_atomic_store((unsigned int*)&hnext[row * HIDDEN + colh], packed,
                                   __ATOMIC_RELAXED, __HIP_MEMORY_SCOPE_AGENT);
            }
            if (last && s == 0) {
                __hip_atomic_store(&hfin[row * HIDDEN + colh], h,
                                   __ATOMIC_RELAXED, __HIP_MEMORY_SCOPE_AGENT);
            }
        }
        // inv every NBUF-th barrier (any fixed phase); t==254 hits phase 2 anyway,
        // covering the hfin handoff to the cached epilogue reads.
        grid_barrier(bar, (unsigned int)(t + 1), (t & 3) == 2 || last);
    }

    // ---- classifier + softmax epilogue: WG b handles batch row b ----
    if (W < BATCH) {
        float part[CLASSES];
        #pragma unroll
        for (int c = 0; c < CLASSES; ++c) part[c] = 0.f;
        for (int k = tid; k < HIDDEN; k += WG_THREADS) {
            float hv = hfin[W * HIDDEN + k];
            #pragma unroll
            for (int c = 0; c < CLASSES; ++c) part[c] += hv * Wph[k * CLASSES + c];
        }
        #pragma unroll
        for (int c = 0; c < CLASSES; ++c)
            for (int off = 32; off > 0; off >>= 1)
                part[c] += __shfl_xor(part[c], off, 64);
        float* red = (float*)lds;
        __syncthreads();
        if (lane == 0)
            for (int c = 0; c < CLASSES; ++c) red[wv * CLASSES + c] = part[c];
        __syncthreads();
        if (tid == 0) {
            float lg[CLASSES];
            for (int c = 0; c < CLASSES; ++c) {
                float sm = bp[c];
                for (int w8 = 0; w8 < 8; ++w8) sm += red[w8 * CLASSES + c];
                lg[c] = sm;
            }
            float mx = lg[0];
            for (int c = 1; c < CLASSES; ++c) mx = fmaxf(mx, lg[c]);
            float se = 0.f;
            for (int c = 0; c < CLASSES; ++c) { lg[c] = __expf(lg[c] - mx); se += lg[c]; }
            float inv = 1.0f / se;
            for (int c = 0; c < CLASSES; ++c) out[W * CLASSES + c] = lg[c] * inv;
        }
    }
}

extern "C" void kernel_launch(void* const* d_in, const int* in_sizes, int n_in,
                              void* d_out, int out_size, void* d_ws, size_t ws_size,
                              hipStream_t stream) {
    const float* x   = (const float*)d_in[0];
    const float* Wx  = (const float*)d_in[1];
    const float* Wh  = (const float*)d_in[2];
    const float* b   = (const float*)d_in[3];
    const float* Wph = (const float*)d_in[4];
    const float* bp  = (const float*)d_in[5];
    float* out = (float*)d_out;

    char* ws = (char*)d_ws;
    unsigned short* whp  = (unsigned short*)(ws + WHP_OFF);
    unsigned short* hbufs= (unsigned short*)(ws + HB_OFF);
    float*          hfin = (float*)(ws + HF_OFF);
    unsigned int*   bar  = (unsigned int*)(ws + BAR_OFF);

    hipFuncSetAttribute((const void*)lstm_persist,
                        hipFuncAttributeMaxDynamicSharedMemorySize, 131072);

    lstm_pack_kernel<<<8192, 256, 0, stream>>>(Wh, whp, hbufs, bar);
    lstm_persist<<<NWG, WG_THREADS, 131072, stream>>>(x, Wx, b, Wph, bp,
                                                      whp, hbufs, hfin, bar, out);
}